// Round 16
// baseline (342.540 us; speedup 1.0000x reference)
//
#include <hip/hip_runtime.h>
#include <hip/hip_bf16.h>

typedef short short8 __attribute__((ext_vector_type(8)));
typedef unsigned short ushort8v __attribute__((ext_vector_type(8)));
typedef float f32x4 __attribute__((ext_vector_type(4)));

#define D_DIM 2048
#define KTOT 4096      // x|h concatenated along K
#define M_TOT 8192     // B*S
#define NPACK 4096     // interleaved Bi|Bc rows

// ---------------- helpers ----------------

__device__ __forceinline__ unsigned short f2bf(float f) {
    union { float f; unsigned u; } c; c.f = f;
    unsigned u = c.u;
    u += 0x7fffu + ((u >> 16) & 1u);   // round-to-nearest-even
    return (unsigned short)(u >> 16);
}

__device__ __forceinline__ float fast_tanh(float x) {
    float ax = fabsf(x);
    float ez = __expf(2.0f * fminf(ax, 15.0f));
    float t = (ez - 1.0f) / (ez + 1.0f);
    return copysignf(t, x);
}

#define GLOAD_LDS16(g, l)                                                     \
    __builtin_amdgcn_global_load_lds(                                         \
        (const __attribute__((address_space(1))) void*)(g),                   \
        (__attribute__((address_space(3))) void*)(l), 16, 0, 0)

#define WAITVM_(N) asm volatile("s_waitcnt vmcnt(" #N ")" ::: "memory")
#define WAITVM(N)  WAITVM_(N)
#define WAITLG_(N) asm volatile("s_waitcnt lgkmcnt(" #N ")" ::: "memory")
#define WAITLG(N)  WAITLG_(N)
#define BAR        __builtin_amdgcn_s_barrier()
#define SCHB       __builtin_amdgcn_sched_barrier(0)
#define PRIO1      __builtin_amdgcn_s_setprio(1)
#define PRIO0      __builtin_amdgcn_s_setprio(0)

// ---------------- pack two f32 [R][2048] matrices into bf16 [R][4096] ------

__global__ __launch_bounds__(256)
void pack2(const float* __restrict__ X, const float* __restrict__ H,
           __hip_bfloat16* __restrict__ dst, int total8) {
    int t = blockIdx.x * 256 + threadIdx.x;
    if (t >= total8) return;
    long e0 = (long)t * 8;
    long r  = e0 >> 12;            // / 4096
    int  k  = (int)(e0 & 4095);
    const float* src = (k < D_DIM) ? (X + r * D_DIM + k)
                                   : (H + r * D_DIM + (k - D_DIM));
    float4 v0 = *(const float4*)(src);
    float4 v1 = *(const float4*)(src + 4);
    ushort8v o;
    o[0] = f2bf(v0.x); o[1] = f2bf(v0.y); o[2] = f2bf(v0.z); o[3] = f2bf(v0.w);
    o[4] = f2bf(v1.x); o[5] = f2bf(v1.y); o[6] = f2bf(v1.z); o[7] = f2bf(v1.w);
    *(ushort8v*)(dst + e0) = o;
}

// ---- pack gate weights, Bi/Bc interleaved in 16-row groups ----------------

__global__ __launch_bounds__(256)
void pack_gates(const float* __restrict__ Wi, const float* __restrict__ Ui,
                const float* __restrict__ Wc, const float* __restrict__ Uc,
                __hip_bfloat16* __restrict__ dst) {
    int t = blockIdx.x * 256 + threadIdx.x;    // 4096*512 threads
    const int g = t >> 9;
    const int k = (t & 511) * 8;
    const int w = g & 31;
    const int n = ((g >> 5) << 4) | (w & 15);
    const float* Wm = (w & 16) ? Wc : Wi;
    const float* Um = (w & 16) ? Uc : Ui;
    const float* src = (k < D_DIM) ? (Wm + (size_t)n * D_DIM + k)
                                   : (Um + (size_t)n * D_DIM + (k - D_DIM));
    float4 v0 = *(const float4*)(src);
    float4 v1 = *(const float4*)(src + 4);
    ushort8v o;
    o[0] = f2bf(v0.x); o[1] = f2bf(v0.y); o[2] = f2bf(v0.z); o[3] = f2bf(v0.w);
    o[4] = f2bf(v1.x); o[5] = f2bf(v1.y); o[6] = f2bf(v1.z); o[7] = f2bf(v1.w);
    *(ushort8v*)(dst + (size_t)g * KTOT + k) = o;
}

// ---------------- 2-phase 256x256 GEMM (R10) + B-panel reuse ---------------
// R10's verified skeleton/ledger. Grid halved to 256 blocks (1/CU); each
// block runs TWO M-tiles (tm0, tm0+256) against the SAME tn: second pass's
// B staging hits warm L2, prologue amortized, one launch round. Ledger at
// the mt-junction: final KTILE's trailing barrier orders all LDS reads
// before mt=1 restaging; prologue vmcnt(8) is conservative wrt epilogue
// stores (stores are older; they drain first).

__device__ __forceinline__ f32x4 mf(short8 a, short8 b, f32x4 c) {
    return __builtin_amdgcn_mfma_f32_16x16x32_bf16(a, b, c, 0, 0, 0);
}

#define RD4A(BUF, IMM)                                                        \
  { _Pragma("unroll") for (int m_ = 0; m_ < 4; ++m_) {                        \
      ak0[m_] = *(const short8*)(rdA0 + (BUF) + (IMM) + m_ * 2048);           \
      ak1[m_] = *(const short8*)(rdA1 + (BUF) + (IMM) + m_ * 2048); } }

#define RDB(d0, d1, BUF, IMM)                                                 \
  { _Pragma("unroll") for (int n_ = 0; n_ < 2; ++n_) {                        \
      d0[n_] = *(const short8*)(rdB0 + (BUF) + (IMM) + n_ * 2048);            \
      d1[n_] = *(const short8*)(rdB1 + (BUF) + (IMM) + n_ * 2048); } }

// 16 MFMA quadrant: 8 independent k0 then 8 k1 (same accumulation order)
#define MF16(MB, NB, bk0, bk1)                                                \
  { _Pragma("unroll") for (int m_ = 0; m_ < 4; ++m_)                          \
    _Pragma("unroll") for (int n_ = 0; n_ < 2; ++n_)                          \
      acc[(MB)+m_][(NB)+n_] = mf(ak0[m_], bk0[n_], acc[(MB)+m_][(NB)+n_]);    \
    _Pragma("unroll") for (int m_ = 0; m_ < 4; ++m_)                          \
    _Pragma("unroll") for (int n_ = 0; n_ < 2; ++n_)                          \
      acc[(MB)+m_][(NB)+n_] = mf(ak1[m_], bk1[n_], acc[(MB)+m_][(NB)+n_]); }

// stage one full tile operand (both 128-row halves, 4 gload_lds / thread)
#define SA(BUFB, KB) { GLOAD_LDS16(gAh0 + (KB), ldsA + (BUFB) + dOff);        \
                       GLOAD_LDS16(gAh0 + (KB) + 524288, ldsA + (BUFB) + dOff + 8192); \
                       GLOAD_LDS16(gAh1 + (KB), ldsA + (BUFB) + 16384 + dOff); \
                       GLOAD_LDS16(gAh1 + (KB) + 524288, ldsA + (BUFB) + 16384 + dOff + 8192); }
#define SBt(BUFB, KB) { GLOAD_LDS16(gBh0 + (KB), ldsB + (BUFB) + dOff);       \
                        GLOAD_LDS16(gBh0 + (KB) + 524288, ldsB + (BUFB) + dOff + 8192); \
                        GLOAD_LDS16(gBh1 + (KB), ldsB + (BUFB) + 16384 + dOff); \
                        GLOAD_LDS16(gBh1 + (KB) + 524288, ldsB + (BUFB) + 16384 + dOff + 8192); }

#define NOSTG (void)0
#define NOVM  (void)0

// one K-tile = 2 phases; BUF in {0, 32768} compile-time
#define KTILE(BUF, S_A, S_B, VMN)                                             \
  { /* PhA */                                                                 \
    RD4A(BUF, 0);                                                             \
    RDB(b01k0, b01k1, BUF, 0);                                                \
    RDB(b23k0, b23k1, BUF, 4096);                                             \
    S_A;                                                                      \
    WAITLG(8);                                                                \
    BAR; WAITLG(0); SCHB;                                                     \
    PRIO1; MF16(0, 0, b01k0, b01k1); MF16(0, 2, b23k0, b23k1); PRIO0; BAR;    \
    /* PhB */                                                                 \
    RD4A(BUF, 8192);                                                          \
    S_B;                                                                      \
    VMN;                                                                      \
    BAR; WAITLG(0); SCHB;                                                     \
    PRIO1; MF16(4, 0, b01k0, b01k1); MF16(4, 2, b23k0, b23k1); PRIO0; BAR;    \
  }

__global__ __launch_bounds__(512, 2)
void gemm8(const __hip_bfloat16* __restrict__ A,
           const __hip_bfloat16* __restrict__ Bp,
           const float* __restrict__ bWi, const float* __restrict__ bUi,
           const float* __restrict__ bWc, const float* __restrict__ bUc,
           float* __restrict__ Cout) {
    // [buf][rowhalf][128 rows][64 cols]; buf stride 32768 B, half 16384 B
    __shared__ __hip_bfloat16 sA[2][2][128][64];
    __shared__ __hip_bfloat16 sB[2][2][128][64];

    const int tid  = threadIdx.x;
    const int wid  = tid >> 6;
    const int lane = tid & 63;

    // XCD swizzle: 256 blocks, 256%8==0 -> bijective
    int bid = blockIdx.x;
    bid = (bid & 7) * 32 + (bid >> 3);
    const int tn  = (bid & 15) * 256;  // Bpack row tile (16 tiles)
    const int tm0 = (bid >> 4) * 512;  // M super-tile (16 of 512 rows)

    const int wr  = (wid >> 2) * 128;  // wave M offset (half = wr>>7)
    const int wc  = (wid & 3) * 64;    // wave Bpack-row offset
    const int r15 = lane & 15;
    const int g   = lane >> 4;

    // read-side swizzled slot bytes (kh=0 / kh=1); balanced across 8 quads
    const int sb    = g ^ (r15 & 3);
    const int khb   = (r15 >> 2) & 1;
    const int slot0 = (khb * 4 + sb) * 16;
    const int slot1 = (((1 ^ khb) * 4) + sb) * 16;

    const char* rdA0 = (const char*)sA + (wr >> 7) * 16384 + r15 * 128 + slot0;
    const char* rdA1 = (const char*)sA + (wr >> 7) * 16384 + r15 * 128 + slot1;
    const char* rdB0 = (const char*)sB + (wc >> 7) * 16384 + (wc & 64) * 128 + r15 * 128 + slot0;
    const char* rdB1 = (const char*)sB + (wc >> 7) * 16384 + (wc & 64) * 128 + r15 * 128 + slot1;

    // ---- hoisted staging addresses ----
    // thread T covers LDS unit T (row r0=T>>3, slot s0=T&7); source col holds
    // the logical (kh,g) stored at that slot: kh=(s0>>2)^r0_2, g=(s0&3)^r0_10
    const int r0 = tid >> 3, s0 = tid & 7;
    const int colb = (((s0 >> 2) ^ ((r0 >> 2) & 1)) * 64) +
                     (((s0 & 3) ^ (r0 & 3)) * 16);
    const char* gBh0 = (const char*)(Bp + (size_t)(tn + r0) * KTOT) + colb;
    const char* gBh1 = gBh0 + (size_t)128 * KTOT * 2;
    char* ldsA = (char*)sA;
    char* ldsB = (char*)sB;
    const int dOff = tid * 16;

    short8 ak0[4], ak1[4], b01k0[2], b01k1[2], b23k0[2], b23k1[2];

    #pragma unroll 1
    for (int mt = 0; mt < 2; ++mt) {
        const int tm = tm0 + mt * 256;
        const char* gAh0 = (const char*)(A + (size_t)(tm + r0) * KTOT) + colb;
        const char* gAh1 = gAh0 + (size_t)128 * KTOT * 2;

        f32x4 acc[8][4] = {};

        // ---- prologue: A(0),B(0),A(1),B(1) = 16 loads; confirm A(0),B(0) --
        SA(0, 0);          SBt(0, 0);            // tile 0 -> buf0
        SA(32768, 128);    SBt(32768, 128);      // tile 1 -> buf1
        WAITVM(8);                               // A(0),B(0) landed (oldest 8)
        BAR;

        // tile 0 (buf0): A(1) already staged; stage B(2)->buf0
        KTILE(0, NOSTG, SBt(0, 256), WAITVM(4));

        int kb = 0;   // = (t-1)*128 where t = first tile of this iteration
        #pragma unroll 1
        for (int i = 0; i < 30; ++i) {           // tiles 1..60
            KTILE(32768, SA(0, kb + 256),     SBt(32768, kb + 384), WAITVM(4));
            KTILE(0,     SA(32768, kb + 384), SBt(0, kb + 512),     WAITVM(4));
            kb += 256;
        }
        // kb = 7680
        KTILE(32768, SA(0, 7936), SBt(32768, 8064), WAITVM(4));   // t=61
        KTILE(0,     SA(32768, 8064), NOSTG,        WAITVM(0));   // t=62
        KTILE(32768, NOSTG, NOSTG, NOVM);                         // t=63

        // ---- epilogue: pair (Zi,Zc) fragments -> c = exp(Zi)*tanh(Zc) ----
        const int rg4 = (lane >> 4) * 4;
        #pragma unroll
        for (int q = 0; q < 2; ++q) {
            const int gn = (tn >> 1) + (wc >> 1) + q * 16 + r15;
            const float bi_ = bWi[gn] + bUi[gn];
            const float bc_ = bWc[gn] + bUc[gn];
            #pragma unroll
            for (int m = 0; m < 8; ++m) {
                const int gm = tm + wr + m * 16 + rg4;
                #pragma unroll
                for (int r = 0; r < 4; ++r) {
                    const float zi = acc[m][2 * q][r]     + bi_;
                    const float zc = acc[m][2 * q + 1][r] + bc_;
                    Cout[(size_t)(gm + r) * D_DIM + gn] = __expf(zi) * fast_tanh(zc);
                }
            }
        }
    }
}

// ---------------- last-timestep o-gate: hbuf[b][e] = sig(Zo)*tanh(c) -------

__global__ __launch_bounds__(256)
void last_gate(const float* __restrict__ x, const float* __restrict__ h,
               const float* __restrict__ Wo, const float* __restrict__ bWo,
               const float* __restrict__ Uo, const float* __restrict__ bUo,
               const float* __restrict__ cfull, float* __restrict__ hbuf) {
    const int o    = blockIdx.x * 4 + (threadIdx.x >> 6);
    const int lane = threadIdx.x & 63;
    const int b = o >> 11, e = o & 2047;
    const float* xr = x  + ((size_t)b * D_DIM + (D_DIM - 1)) * D_DIM;
    const float* hr = h  + ((size_t)b * D_DIM + (D_DIM - 1)) * D_DIM;
    const float* wo = Wo + (size_t)e * D_DIM;
    const float* uo = Uo + (size_t)e * D_DIM;
    float s = 0.0f;
    for (int d = lane; d < D_DIM; d += 64)
        s += xr[d] * wo[d] + hr[d] * uo[d];
    #pragma unroll
    for (int off = 32; off; off >>= 1) s += __shfl_down(s, off);
    if (lane == 0) {
        const float zo  = s + bWo[e] + bUo[e];
        const float sig = 1.0f / (1.0f + __expf(-zo));
        const float cv  = cfull[((size_t)b * D_DIM + (D_DIM - 1)) * D_DIM + e];
        hbuf[o] = sig * fast_tanh(cv);
    }
}

// ---------------- final projection: out[b][p] = hbuf[b] . Wp[p] + bp[p] ----

__global__ __launch_bounds__(256)
void proj(const float* __restrict__ hbuf, const float* __restrict__ Wp,
          const float* __restrict__ bp, float* __restrict__ out) {
    const int o    = blockIdx.x * 4 + (threadIdx.x >> 6);
    const int lane = threadIdx.x & 63;
    const int b = o >> 11, p = o & 2047;
    const float* hv = hbuf + (size_t)b * D_DIM;
    const float* wp = Wp   + (size_t)p * D_DIM;
    float s = 0.0f;
    for (int e = lane; e < D_DIM; e += 64)
        s += hv[e] * wp[e];
    #pragma unroll
    for (int off = 32; off; off >>= 1) s += __shfl_down(s, off);
    if (lane == 0) out[o] = s + bp[p];
}

// ---------------- launch ---------------------------------------------------

extern "C" void kernel_launch(void* const* d_in, const int* in_sizes, int n_in,
                              void* d_out, int out_size, void* d_ws, size_t ws_size,
                              hipStream_t stream) {
    const float* x   = (const float*)d_in[0];
    const float* h   = (const float*)d_in[1];
    const float* Wi  = (const float*)d_in[2];  const float* bWi = (const float*)d_in[3];
    const float* Ui  = (const float*)d_in[4];  const float* bUi = (const float*)d_in[5];
    // Wf/bWf/Uf/bUf (6..9) are dead: f-gate multiplies a zero cell state
    const float* Wc  = (const float*)d_in[10]; const float* bWc = (const float*)d_in[11];
    const float* Uc  = (const float*)d_in[12]; const float* bUc = (const float*)d_in[13];
    const float* Wo  = (const float*)d_in[14]; const float* bWo = (const float*)d_in[15];
    const float* Uo  = (const float*)d_in[16]; const float* bUo = (const float*)d_in[17];
    const float* Wp  = (const float*)d_in[18]; const float* bp  = (const float*)d_in[19];

    float* out = (float*)d_out;               // [0,8192) hidden_state, then c
    char*  ws  = (char*)d_ws;

    __hip_bfloat16* Abf  = (__hip_bfloat16*)ws;                          // 64 MiB
    __hip_bfloat16* Bpk  = (__hip_bfloat16*)(ws + ((size_t)64 << 20));   // 32 MiB
    float*          hbuf = (float*)(ws + ((size_t)96 << 20));            // 32 KiB

    // 1) convert/pack to bf16
    pack2<<<16384, 256, 0, stream>>>(x, h, Abf, M_TOT * KTOT / 8);
    pack_gates<<<8192, 256, 0, stream>>>(Wi, Ui, Wc, Uc, Bpk);

    // 2) fused dual-gate GEMM -> c  (256 blocks, 2 M-tiles each)
    gemm8<<<(M_TOT / 512) * (NPACK / 256), 512, 0, stream>>>(
        Abf, Bpk, bWi, bUi, bWc, bUc, out + 8192);

    // 3) last-timestep o-gate (reads c from out), then 4) projection
    last_gate<<<2048, 256, 0, stream>>>(x, h, Wo, bWo, Uo, bUo, out + 8192,
                                        (float*)hbuf);
    proj<<<2048, 256, 0, stream>>>(hbuf, Wp, bp, out);
}

// Round 17
// 317.369 us; speedup vs baseline: 1.0793x; 1.0793x over previous
//
#include <hip/hip_runtime.h>
#include <hip/hip_bf16.h>

typedef short short8 __attribute__((ext_vector_type(8)));
typedef unsigned short ushort8v __attribute__((ext_vector_type(8)));
typedef float f32x4 __attribute__((ext_vector_type(4)));

#define D_DIM 2048
#define KTOT 4096      // x|h concatenated along K
#define M_TOT 8192     // B*S
#define NPACK 4096     // interleaved Bi|Bc rows

// ---------------- helpers ----------------

__device__ __forceinline__ unsigned short f2bf(float f) {
    union { float f; unsigned u; } c; c.f = f;
    unsigned u = c.u;
    u += 0x7fffu + ((u >> 16) & 1u);   // round-to-nearest-even
    return (unsigned short)(u >> 16);
}

__device__ __forceinline__ float fast_tanh(float x) {
    float ax = fabsf(x);
    float ez = __expf(2.0f * fminf(ax, 15.0f));
    float t = (ez - 1.0f) / (ez + 1.0f);
    return copysignf(t, x);
}

#define GLOAD_LDS16(g, l)                                                     \
    __builtin_amdgcn_global_load_lds(                                         \
        (const __attribute__((address_space(1))) void*)(g),                   \
        (__attribute__((address_space(3))) void*)(l), 16, 0, 0)

#define WAITVM_(N) asm volatile("s_waitcnt vmcnt(" #N ")" ::: "memory")
#define WAITVM(N)  WAITVM_(N)
#define WAITLG_(N) asm volatile("s_waitcnt lgkmcnt(" #N ")" ::: "memory")
#define WAITLG(N)  WAITLG_(N)
#define BAR        __builtin_amdgcn_s_barrier()
#define SCHB       __builtin_amdgcn_sched_barrier(0)
#define PRIO1      __builtin_amdgcn_s_setprio(1)
#define PRIO0      __builtin_amdgcn_s_setprio(0)

// ------- merged pack kernel: pack2 (x|h -> A) and pack_gates (Bpack) -------
// blocks [0, 16384): A-pack; blocks [16384, 24576): gate-pack. Branch is
// block-uniform; bodies identical to the verified separate kernels.

__global__ __launch_bounds__(256)
void packall(const float* __restrict__ X, const float* __restrict__ H,
             __hip_bfloat16* __restrict__ dstA,
             const float* __restrict__ Wi, const float* __restrict__ Ui,
             const float* __restrict__ Wc, const float* __restrict__ Uc,
             __hip_bfloat16* __restrict__ dstB) {
    const int bid = blockIdx.x;
    if (bid < 16384) {
        // ---- A-pack: two f32 [8192][2048] -> bf16 [8192][4096] ----
        int t = bid * 256 + threadIdx.x;
        long e0 = (long)t * 8;
        long r  = e0 >> 12;            // / 4096
        int  k  = (int)(e0 & 4095);
        const float* src = (k < D_DIM) ? (X + r * D_DIM + k)
                                       : (H + r * D_DIM + (k - D_DIM));
        float4 v0 = *(const float4*)(src);
        float4 v1 = *(const float4*)(src + 4);
        ushort8v o;
        o[0] = f2bf(v0.x); o[1] = f2bf(v0.y); o[2] = f2bf(v0.z); o[3] = f2bf(v0.w);
        o[4] = f2bf(v1.x); o[5] = f2bf(v1.y); o[6] = f2bf(v1.z); o[7] = f2bf(v1.w);
        *(ushort8v*)(dstA + e0) = o;
    } else {
        // ---- gate-pack: Bpack row g: f=g>>5, w=g&31; gate=(w>>4);
        // source n = f*16 + (w&15); cols [0,2048)=W[n], [2048,4096)=U[n] ----
        int t = (bid - 16384) * 256 + threadIdx.x;
        const int g = t >> 9;
        const int k = (t & 511) * 8;
        const int w = g & 31;
        const int n = ((g >> 5) << 4) | (w & 15);
        const float* Wm = (w & 16) ? Wc : Wi;
        const float* Um = (w & 16) ? Uc : Ui;
        const float* src = (k < D_DIM) ? (Wm + (size_t)n * D_DIM + k)
                                       : (Um + (size_t)n * D_DIM + (k - D_DIM));
        float4 v0 = *(const float4*)(src);
        float4 v1 = *(const float4*)(src + 4);
        ushort8v o;
        o[0] = f2bf(v0.x); o[1] = f2bf(v0.y); o[2] = f2bf(v0.z); o[3] = f2bf(v0.w);
        o[4] = f2bf(v1.x); o[5] = f2bf(v1.y); o[6] = f2bf(v1.z); o[7] = f2bf(v1.w);
        *(ushort8v*)(dstB + (size_t)g * KTOT + k) = o;
    }
}

// ---------------- 2-phase 256x256 fused GEMM (verified R10) ----------------
// PhA: read A m0-3 (8) + B n0-3 (8); stage A(t+1); lgkm(8); bar; lgkm(0);
//      32 MFMA m0-3 x n0-3; bar.
// PhB: read A m4-7 (8); stage B(t+2) into CUR B-buf (B(t) reads completed
//      in PhA); vmcnt(4); bar; lgkm(0); 32 MFMA m4-7 x n0-3; bar.
// Steady ledger at PhB wait: B(t+1)[4] + A(t+1)[4] + B(t+2)[4] = 12 in
// flight -> vmcnt(4) confirms exactly B(t+1)+A(t+1).

__device__ __forceinline__ f32x4 mf(short8 a, short8 b, f32x4 c) {
    return __builtin_amdgcn_mfma_f32_16x16x32_bf16(a, b, c, 0, 0, 0);
}

#define RD4A(BUF, IMM)                                                        \
  { _Pragma("unroll") for (int m_ = 0; m_ < 4; ++m_) {                        \
      ak0[m_] = *(const short8*)(rdA0 + (BUF) + (IMM) + m_ * 2048);           \
      ak1[m_] = *(const short8*)(rdA1 + (BUF) + (IMM) + m_ * 2048); } }

#define RDB(d0, d1, BUF, IMM)                                                 \
  { _Pragma("unroll") for (int n_ = 0; n_ < 2; ++n_) {                        \
      d0[n_] = *(const short8*)(rdB0 + (BUF) + (IMM) + n_ * 2048);            \
      d1[n_] = *(const short8*)(rdB1 + (BUF) + (IMM) + n_ * 2048); } }

// 16 MFMA quadrant: 8 independent k0 then 8 k1 (same accumulation order)
#define MF16(MB, NB, bk0, bk1)                                                \
  { _Pragma("unroll") for (int m_ = 0; m_ < 4; ++m_)                          \
    _Pragma("unroll") for (int n_ = 0; n_ < 2; ++n_)                          \
      acc[(MB)+m_][(NB)+n_] = mf(ak0[m_], bk0[n_], acc[(MB)+m_][(NB)+n_]);    \
    _Pragma("unroll") for (int m_ = 0; m_ < 4; ++m_)                          \
    _Pragma("unroll") for (int n_ = 0; n_ < 2; ++n_)                          \
      acc[(MB)+m_][(NB)+n_] = mf(ak1[m_], bk1[n_], acc[(MB)+m_][(NB)+n_]); }

// stage one full tile operand (both 128-row halves, 4 gload_lds / thread)
#define SA(BUFB, KB) { GLOAD_LDS16(gAh0 + (KB), ldsA + (BUFB) + dOff);        \
                       GLOAD_LDS16(gAh0 + (KB) + 524288, ldsA + (BUFB) + dOff + 8192); \
                       GLOAD_LDS16(gAh1 + (KB), ldsA + (BUFB) + 16384 + dOff); \
                       GLOAD_LDS16(gAh1 + (KB) + 524288, ldsA + (BUFB) + 16384 + dOff + 8192); }
#define SBt(BUFB, KB) { GLOAD_LDS16(gBh0 + (KB), ldsB + (BUFB) + dOff);       \
                        GLOAD_LDS16(gBh0 + (KB) + 524288, ldsB + (BUFB) + dOff + 8192); \
                        GLOAD_LDS16(gBh1 + (KB), ldsB + (BUFB) + 16384 + dOff); \
                        GLOAD_LDS16(gBh1 + (KB) + 524288, ldsB + (BUFB) + 16384 + dOff + 8192); }

#define NOSTG (void)0
#define NOVM  (void)0

// one K-tile = 2 phases; BUF in {0, 32768} compile-time
#define KTILE(BUF, S_A, S_B, VMN)                                             \
  { /* PhA */                                                                 \
    RD4A(BUF, 0);                                                             \
    RDB(b01k0, b01k1, BUF, 0);                                                \
    RDB(b23k0, b23k1, BUF, 4096);                                             \
    S_A;                                                                      \
    WAITLG(8);                                                                \
    BAR; WAITLG(0); SCHB;                                                     \
    PRIO1; MF16(0, 0, b01k0, b01k1); MF16(0, 2, b23k0, b23k1); PRIO0; BAR;    \
    /* PhB */                                                                 \
    RD4A(BUF, 8192);                                                          \
    S_B;                                                                      \
    VMN;                                                                      \
    BAR; WAITLG(0); SCHB;                                                     \
    PRIO1; MF16(4, 0, b01k0, b01k1); MF16(4, 2, b23k0, b23k1); PRIO0; BAR;    \
  }

__global__ __launch_bounds__(512, 2)
void gemm8(const __hip_bfloat16* __restrict__ A,
           const __hip_bfloat16* __restrict__ Bp,
           const float* __restrict__ bWi, const float* __restrict__ bUi,
           const float* __restrict__ bWc, const float* __restrict__ bUc,
           float* __restrict__ Cout) {
    // [buf][rowhalf][128 rows][64 cols]; buf stride 32768 B, half 16384 B
    __shared__ __hip_bfloat16 sA[2][2][128][64];
    __shared__ __hip_bfloat16 sB[2][2][128][64];

    const int tid  = threadIdx.x;
    const int wid  = tid >> 6;
    const int lane = tid & 63;

    // XCD swizzle: 512 blocks, 512%8==0 -> bijective
    int bid = blockIdx.x;
    bid = (bid & 7) * 64 + (bid >> 3);
    const int tn = (bid & 15) * 256;   // Bpack row tile (16 tiles)
    const int tm = (bid >> 4) * 256;   // M tile (32 tiles)

    const int wr  = (wid >> 2) * 128;  // wave M offset (half = wr>>7)
    const int wc  = (wid & 3) * 64;    // wave Bpack-row offset
    const int r15 = lane & 15;
    const int g   = lane >> 4;

    // read-side swizzled slot bytes (kh=0 / kh=1); balanced across 8 quads
    const int sb    = g ^ (r15 & 3);
    const int khb   = (r15 >> 2) & 1;
    const int slot0 = (khb * 4 + sb) * 16;
    const int slot1 = (((1 ^ khb) * 4) + sb) * 16;

    const char* rdA0 = (const char*)sA + (wr >> 7) * 16384 + r15 * 128 + slot0;
    const char* rdA1 = (const char*)sA + (wr >> 7) * 16384 + r15 * 128 + slot1;
    const char* rdB0 = (const char*)sB + (wc >> 7) * 16384 + (wc & 64) * 128 + r15 * 128 + slot0;
    const char* rdB1 = (const char*)sB + (wc >> 7) * 16384 + (wc & 64) * 128 + r15 * 128 + slot1;

    // ---- hoisted staging addresses ----
    // thread T covers LDS unit T (row r0=T>>3, slot s0=T&7); source col holds
    // the logical (kh,g) stored at that slot: kh=(s0>>2)^r0_2, g=(s0&3)^r0_10
    const int r0 = tid >> 3, s0 = tid & 7;
    const int colb = (((s0 >> 2) ^ ((r0 >> 2) & 1)) * 64) +
                     (((s0 & 3) ^ (r0 & 3)) * 16);
    const char* gAh0 = (const char*)(A  + (size_t)(tm + r0) * KTOT) + colb;
    const char* gAh1 = gAh0 + (size_t)128 * KTOT * 2;
    const char* gBh0 = (const char*)(Bp + (size_t)(tn + r0) * KTOT) + colb;
    const char* gBh1 = gBh0 + (size_t)128 * KTOT * 2;
    char* ldsA = (char*)sA;
    char* ldsB = (char*)sB;
    const int dOff = tid * 16;

    f32x4 acc[8][4] = {};
    short8 ak0[4], ak1[4], b01k0[2], b01k1[2], b23k0[2], b23k1[2];

    // ---- prologue: A(0),B(0),A(1),B(1) = 16 loads; confirm A(0),B(0) ----
    SA(0, 0);          SBt(0, 0);            // tile 0 -> buf0
    SA(32768, 128);    SBt(32768, 128);      // tile 1 -> buf1
    WAITVM(8);                               // A(0),B(0) landed (oldest 8)
    BAR;

    // tile 0 (buf0): A(1) already staged; stage B(2)->buf0
    KTILE(0, NOSTG, SBt(0, 256), WAITVM(4));

    int kb = 0;   // = (t-1)*128 where t = first tile of this iteration
    #pragma unroll 1
    for (int i = 0; i < 30; ++i) {           // tiles 1..60
        KTILE(32768, SA(0, kb + 256),     SBt(32768, kb + 384), WAITVM(4));
        KTILE(0,     SA(32768, kb + 384), SBt(0, kb + 512),     WAITVM(4));
        kb += 256;
    }
    // kb = 7680
    KTILE(32768, SA(0, 7936), SBt(32768, 8064), WAITVM(4));   // t=61
    KTILE(0,     SA(32768, 8064), NOSTG,        WAITVM(0));   // t=62
    KTILE(32768, NOSTG, NOSTG, NOVM);                         // t=63

    // ---- epilogue: pair (Zi,Zc) fragments -> c = exp(Zi)*tanh(Zc) ----
    const int rg4 = (lane >> 4) * 4;
    #pragma unroll
    for (int q = 0; q < 2; ++q) {
        const int gn = (tn >> 1) + (wc >> 1) + q * 16 + r15;
        const float bi_ = bWi[gn] + bUi[gn];
        const float bc_ = bWc[gn] + bUc[gn];
        #pragma unroll
        for (int m = 0; m < 8; ++m) {
            const int gm = tm + wr + m * 16 + rg4;
            #pragma unroll
            for (int r = 0; r < 4; ++r) {
                const float zi = acc[m][2 * q][r]     + bi_;
                const float zc = acc[m][2 * q + 1][r] + bc_;
                Cout[(size_t)(gm + r) * D_DIM + gn] = __expf(zi) * fast_tanh(zc);
            }
        }
    }
}

// ---------------- last-timestep o-gate: hbuf[b][e] = sig(Zo)*tanh(c) -------

__global__ __launch_bounds__(256)
void last_gate(const float* __restrict__ x, const float* __restrict__ h,
               const float* __restrict__ Wo, const float* __restrict__ bWo,
               const float* __restrict__ Uo, const float* __restrict__ bUo,
               const float* __restrict__ cfull, float* __restrict__ hbuf) {
    const int o    = blockIdx.x * 4 + (threadIdx.x >> 6);
    const int lane = threadIdx.x & 63;
    const int b = o >> 11, e = o & 2047;
    const float* xr = x  + ((size_t)b * D_DIM + (D_DIM - 1)) * D_DIM;
    const float* hr = h  + ((size_t)b * D_DIM + (D_DIM - 1)) * D_DIM;
    const float* wo = Wo + (size_t)e * D_DIM;
    const float* uo = Uo + (size_t)e * D_DIM;
    float s = 0.0f;
    for (int d = lane; d < D_DIM; d += 64)
        s += xr[d] * wo[d] + hr[d] * uo[d];
    #pragma unroll
    for (int off = 32; off; off >>= 1) s += __shfl_down(s, off);
    if (lane == 0) {
        const float zo  = s + bWo[e] + bUo[e];
        const float sig = 1.0f / (1.0f + __expf(-zo));
        const float cv  = cfull[((size_t)b * D_DIM + (D_DIM - 1)) * D_DIM + e];
        hbuf[o] = sig * fast_tanh(cv);
    }
}

// ---------------- final projection: out[b][p] = hbuf[b] . Wp[p] + bp[p] ----

__global__ __launch_bounds__(256)
void proj(const float* __restrict__ hbuf, const float* __restrict__ Wp,
          const float* __restrict__ bp, float* __restrict__ out) {
    const int o    = blockIdx.x * 4 + (threadIdx.x >> 6);
    const int lane = threadIdx.x & 63;
    const int b = o >> 11, p = o & 2047;
    const float* hv = hbuf + (size_t)b * D_DIM;
    const float* wp = Wp   + (size_t)p * D_DIM;
    float s = 0.0f;
    for (int e = lane; e < D_DIM; e += 64)
        s += hv[e] * wp[e];
    #pragma unroll
    for (int off = 32; off; off >>= 1) s += __shfl_down(s, off);
    if (lane == 0) out[o] = s + bp[p];
}

// ---------------- launch ---------------------------------------------------

extern "C" void kernel_launch(void* const* d_in, const int* in_sizes, int n_in,
                              void* d_out, int out_size, void* d_ws, size_t ws_size,
                              hipStream_t stream) {
    const float* x   = (const float*)d_in[0];
    const float* h   = (const float*)d_in[1];
    const float* Wi  = (const float*)d_in[2];  const float* bWi = (const float*)d_in[3];
    const float* Ui  = (const float*)d_in[4];  const float* bUi = (const float*)d_in[5];
    // Wf/bWf/Uf/bUf (6..9) are dead: f-gate multiplies a zero cell state
    const float* Wc  = (const float*)d_in[10]; const float* bWc = (const float*)d_in[11];
    const float* Uc  = (const float*)d_in[12]; const float* bUc = (const float*)d_in[13];
    const float* Wo  = (const float*)d_in[14]; const float* bWo = (const float*)d_in[15];
    const float* Uo  = (const float*)d_in[16]; const float* bUo = (const float*)d_in[17];
    const float* Wp  = (const float*)d_in[18]; const float* bp  = (const float*)d_in[19];

    float* out = (float*)d_out;               // [0,8192) hidden_state, then c
    char*  ws  = (char*)d_ws;

    __hip_bfloat16* Abf  = (__hip_bfloat16*)ws;                          // 64 MiB
    __hip_bfloat16* Bpk  = (__hip_bfloat16*)(ws + ((size_t)64 << 20));   // 32 MiB
    float*          hbuf = (float*)(ws + ((size_t)96 << 20));            // 32 KiB

    // 1) convert/pack to bf16 (A-pack + gate-pack merged, one launch)
    packall<<<24576, 256, 0, stream>>>(x, h, Abf, Wi, Ui, Wc, Uc, Bpk);

    // 2) fused dual-gate GEMM -> c
    gemm8<<<(M_TOT / 256) * (NPACK / 256), 512, 0, stream>>>(
        Abf, Bpk, bWi, bUi, bWc, bUc, out + 8192);

    // 3) last-timestep o-gate (reads c from out), then 4) projection
    last_gate<<<2048, 256, 0, stream>>>(x, h, Wo, bWo, Uo, bUo, out + 8192,
                                        (float*)hbuf);
    proj<<<2048, 256, 0, stream>>>(hbuf, Wp, bp, out);
}